// Round 1
// baseline (160.990 us; speedup 1.0000x reference)
//
#include <hip/hip_runtime.h>
#include <hip/hip_bf16.h>
#include <stdint.h>

// SimCLR loss, B=4096, D=256, T=0.1.
// loss = (1/2B) * sum_i [ log(sum_{j!=i} exp(sim_ij)) - sim_{i,pair(i)} ]
// sim bounded in [-10,10] => no max-subtraction needed for logsumexp.

#define BROWS 4096
#define NROWS 8192   // 2B
#define DDIM  256
#define TINV  10.0f
#define EPSN  1e-8f

typedef __bf16 bf16;
typedef bf16  bf16x4 __attribute__((ext_vector_type(4)));
typedef bf16  bf16x8 __attribute__((ext_vector_type(8)));
typedef float f32x4  __attribute__((ext_vector_type(4)));

// ---------------- normalize: fp32 in -> unit rows, bf16 out + norms --------
__global__ __launch_bounds__(256) void norm_kernel(
    const float* __restrict__ z1, const float* __restrict__ z2,
    bf16* __restrict__ zn, float* __restrict__ norms) {
  int row  = blockIdx.x * 4 + (threadIdx.x >> 6);   // 4 rows per block (1/wave)
  int lane = threadIdx.x & 63;
  const float* src = (row < BROWS) ? (z1 + (size_t)row * DDIM)
                                   : (z2 + (size_t)(row - BROWS) * DDIM);
  float4 v = ((const float4*)src)[lane];            // 64 lanes * 4 = 256
  float ss = v.x*v.x + v.y*v.y + v.z*v.z + v.w*v.w;
  #pragma unroll
  for (int off = 32; off; off >>= 1) ss += __shfl_xor(ss, off, 64);
  float nrm = fmaxf(sqrtf(ss), EPSN);
  if (lane == 0) norms[row] = nrm;
  float inv = 1.0f / nrm;
  bf16x4 o;
  o[0] = (bf16)(v.x * inv); o[1] = (bf16)(v.y * inv);
  o[2] = (bf16)(v.z * inv); o[3] = (bf16)(v.w * inv);
  *(bf16x4*)(zn + (size_t)row * DDIM + lane * 4) = o;
}

// ---------------- positive pair logits in fp32 -----------------------------
__global__ __launch_bounds__(256) void pos_kernel(
    const float* __restrict__ z1, const float* __restrict__ z2,
    const float* __restrict__ norms, float* __restrict__ pos) {
  int i    = blockIdx.x * 4 + (threadIdx.x >> 6);
  int lane = threadIdx.x & 63;
  float4 a = ((const float4*)(z1 + (size_t)i * DDIM))[lane];
  float4 b = ((const float4*)(z2 + (size_t)i * DDIM))[lane];
  float d = a.x*b.x + a.y*b.y + a.z*b.z + a.w*b.w;
  #pragma unroll
  for (int off = 32; off; off >>= 1) d += __shfl_xor(d, off, 64);
  if (lane == 0) pos[i] = d / (norms[i] * norms[i + BROWS]) * TINV;
}

// ---------------- async global->LDS, 16B ----------------------------------
__device__ __forceinline__ void async16(const bf16* g, bf16* l) {
  __builtin_amdgcn_global_load_lds(
      (const __attribute__((address_space(1))) unsigned int*)g,
      (__attribute__((address_space(3))) unsigned int*)l,
      16, 0, 0);
}

// ---------------- fused Gram-tile + exp + row-sum --------------------------
// 128x128 tile per block, 4 waves in 2x2 grid of 64x64, BK=64, K=256.
// LDS layout: per row of 8 chunks (16B each), chunk slot c8 holds global
// chunk (c8 ^ (row&7))  -> swizzle folded into global address so the
// global_load_lds wave-uniform-base constraint holds, and ds_read_b128
// fragment reads hit all 32 banks.
#define TM 128
#define BK 64

__global__ __launch_bounds__(256) void simexp_kernel(
    const bf16* __restrict__ zn, float* __restrict__ rowsum) {
  __shared__ __align__(16) bf16 ldsA[TM * BK];   // 16 KB
  __shared__ __align__(16) bf16 ldsB[TM * BK];   // 16 KB

  const int bi = blockIdx.y, bj = blockIdx.x;
  const int t = threadIdx.x;
  const int wave = t >> 6, lane = t & 63;
  const int wr = wave >> 1, wc = wave & 1;       // 2x2 wave grid
  const int quad = lane >> 4, l15 = lane & 15;
  const int rowA0 = bi * TM, rowB0 = bj * TM;

  f32x4 acc[4][4] = {};

  for (int k0 = 0; k0 < DDIM; k0 += BK) {
    __syncthreads();                              // LDS reuse across k-iters
    #pragma unroll
    for (int p = 0; p < 4; ++p) {                 // 1024 chunks / 256 thr
      int c = p * 256 + t;
      int row = c >> 3, c8 = c & 7;
      int gc8 = c8 ^ (row & 7);                   // swizzle in global addr
      const bf16* gA = zn + (size_t)(rowA0 + row) * DDIM + k0 + gc8 * 8;
      const bf16* gB = zn + (size_t)(rowB0 + row) * DDIM + k0 + gc8 * 8;
      async16(gA, &ldsA[c * 8]);
      async16(gB, &ldsB[c * 8]);
    }
    __syncthreads();

    #pragma unroll
    for (int kk = 0; kk < BK; kk += 32) {
      const int kc8 = (kk >> 3) + quad;           // K-chunk this lane wants
      bf16x8 af[4], bg[4];
      #pragma unroll
      for (int mi = 0; mi < 4; ++mi) {
        int row = wr * 64 + mi * 16 + l15;
        int sc8 = kc8 ^ (row & 7);
        af[mi] = *(const bf16x8*)&ldsA[(row * 8 + sc8) * 8];
      }
      #pragma unroll
      for (int nj = 0; nj < 4; ++nj) {
        int row = wc * 64 + nj * 16 + l15;
        int sc8 = kc8 ^ (row & 7);
        bg[nj] = *(const bf16x8*)&ldsB[(row * 8 + sc8) * 8];
      }
      #pragma unroll
      for (int mi = 0; mi < 4; ++mi)
        #pragma unroll
        for (int nj = 0; nj < 4; ++nj)
          acc[mi][nj] = __builtin_amdgcn_mfma_f32_16x16x32_bf16(
              af[mi], bg[nj], acc[mi][nj], 0, 0, 0);
    }
  }

  // Epilogue: exp (diag masked), sum over 64 cols per row, atomic per row.
  #pragma unroll
  for (int mi = 0; mi < 4; ++mi) {
    float rs[4] = {0.f, 0.f, 0.f, 0.f};
    #pragma unroll
    for (int nj = 0; nj < 4; ++nj) {
      int gj = rowB0 + wc * 64 + nj * 16 + l15;
      #pragma unroll
      for (int r = 0; r < 4; ++r) {
        int gi = rowA0 + wr * 64 + mi * 16 + quad * 4 + r;
        float e = __expf(acc[mi][nj][r] * TINV);
        rs[r] += (gi == gj) ? 0.f : e;
      }
    }
    #pragma unroll
    for (int r = 0; r < 4; ++r) {
      float s = rs[r];
      s += __shfl_xor(s, 1, 64);
      s += __shfl_xor(s, 2, 64);
      s += __shfl_xor(s, 4, 64);
      s += __shfl_xor(s, 8, 64);
      if (l15 == 0) {
        int gi = rowA0 + wr * 64 + mi * 16 + quad * 4 + r;
        atomicAdd(&rowsum[gi], s);
      }
    }
  }
}

// ---------------- final scalar reduction -----------------------------------
__global__ __launch_bounds__(256) void finalize_kernel(
    const float* __restrict__ rowsum, const float* __restrict__ pos,
    float* __restrict__ out) {
  __shared__ float red[4];
  int t = threadIdx.x;
  float s = 0.f;
  for (int i = t; i < NROWS; i += 256) s += __logf(rowsum[i]);
  for (int i = t; i < BROWS; i += 256) s -= 2.f * pos[i];
  #pragma unroll
  for (int off = 32; off; off >>= 1) s += __shfl_xor(s, off, 64);
  if ((t & 63) == 0) red[t >> 6] = s;
  __syncthreads();
  if (t == 0) out[0] = (red[0] + red[1] + red[2] + red[3]) / (float)NROWS;
}

// ---------------- launch ----------------------------------------------------
extern "C" void kernel_launch(void* const* d_in, const int* in_sizes, int n_in,
                              void* d_out, int out_size, void* d_ws, size_t ws_size,
                              hipStream_t stream) {
  const float* z1 = (const float*)d_in[0];
  const float* z2 = (const float*)d_in[1];
  char* ws = (char*)d_ws;
  bf16*  zn     = (bf16*)ws;                               // 4 MB
  float* norms  = (float*)(ws + 4194304);                  // 32 KB
  float* rowsum = (float*)(ws + 4194304 + 32768);          // 32 KB
  float* pos    = (float*)(ws + 4194304 + 65536);          // 16 KB
  float* out    = (float*)d_out;

  hipMemsetAsync(rowsum, 0, NROWS * sizeof(float), stream);
  norm_kernel<<<NROWS / 4, 256, 0, stream>>>(z1, z2, zn, norms);
  pos_kernel<<<BROWS / 4, 256, 0, stream>>>(z1, z2, norms, pos);
  dim3 grid(NROWS / TM, NROWS / TM);
  simexp_kernel<<<grid, 256, 0, stream>>>(zn, rowsum);
  finalize_kernel<<<1, 256, 0, stream>>>(rowsum, pos, out);
}

// Round 2
// 134.650 us; speedup vs baseline: 1.1956x; 1.1956x over previous
//
#include <hip/hip_runtime.h>
#include <hip/hip_bf16.h>
#include <stdint.h>

// SimCLR loss, B=4096, D=256, T=0.1.
// loss = (1/2B) * sum_i [ log(sum_{j!=i} exp(sim_ij)) - sim_{i,pair(i)} ]
// sim in [-10,10] => no max-subtraction needed.
// sim is SYMMETRIC: compute lower-triangle tiles only; off-diag tiles
// contribute row-sums to rowsum[i] and col-sums to rowsum[j].

#define BROWS 4096
#define NROWS 8192   // 2B
#define DDIM  256
#define TINV  10.0f
#define EPSN  1e-8f

typedef __bf16 bf16;
typedef bf16  bf16x4 __attribute__((ext_vector_type(4)));
typedef bf16  bf16x8 __attribute__((ext_vector_type(8)));
typedef float f32x4  __attribute__((ext_vector_type(4)));

// ------- prep: norms + bf16 unit rows + positive logits + rowsum zero ------
// 1024 blocks x 4 waves; wave w handles pair-row i = blockIdx*4 + w:
// reads z1[i], z2[i] once, emits zn[i], zn[i+B], pos[i].
__global__ __launch_bounds__(256) void prep_kernel(
    const float* __restrict__ z1, const float* __restrict__ z2,
    bf16* __restrict__ zn, float* __restrict__ pos,
    float* __restrict__ rowsum) {
  int t = threadIdx.x;
  int i    = blockIdx.x * 4 + (t >> 6);
  int lane = t & 63;
  if (blockIdx.x < 32) rowsum[blockIdx.x * 256 + t] = 0.f;   // zero 8192 f32

  float4 a = ((const float4*)(z1 + (size_t)i * DDIM))[lane];
  float4 b = ((const float4*)(z2 + (size_t)i * DDIM))[lane];
  float s1 = a.x*a.x + a.y*a.y + a.z*a.z + a.w*a.w;
  float s2 = b.x*b.x + b.y*b.y + b.z*b.z + b.w*b.w;
  float dt = a.x*b.x + a.y*b.y + a.z*b.z + a.w*b.w;
  #pragma unroll
  for (int off = 32; off; off >>= 1) {
    s1 += __shfl_xor(s1, off, 64);
    s2 += __shfl_xor(s2, off, 64);
    dt += __shfl_xor(dt, off, 64);
  }
  float n1 = fmaxf(sqrtf(s1), EPSN), n2 = fmaxf(sqrtf(s2), EPSN);
  float i1 = 1.0f / n1, i2 = 1.0f / n2;
  if (lane == 0) pos[i] = dt * i1 * i2 * TINV;
  bf16x4 o1, o2;
  o1[0] = (bf16)(a.x*i1); o1[1] = (bf16)(a.y*i1);
  o1[2] = (bf16)(a.z*i1); o1[3] = (bf16)(a.w*i1);
  o2[0] = (bf16)(b.x*i2); o2[1] = (bf16)(b.y*i2);
  o2[2] = (bf16)(b.z*i2); o2[3] = (bf16)(b.w*i2);
  *(bf16x4*)(zn + (size_t)i * DDIM + lane * 4) = o1;
  *(bf16x4*)(zn + (size_t)(i + BROWS) * DDIM + lane * 4) = o2;
}

// ---------------- async global->LDS, 16B ----------------------------------
__device__ __forceinline__ void async16(const bf16* g, bf16* l) {
  __builtin_amdgcn_global_load_lds(
      (const __attribute__((address_space(1))) unsigned int*)g,
      (__attribute__((address_space(3))) unsigned int*)l,
      16, 0, 0);
}

// ---------------- fused Gram-tile + exp + row/col sums ---------------------
// Lower-triangle 128x128 tiles; 4 waves in 2x2 grid of 64x64, BK=64.
// XOR-swizzled LDS chunk layout folded into the global address (keeps the
// global_load_lds wave-uniform-base rule; ds_read_b128 spreads banks).
#define TM 128
#define BK 64
#define NTILE (NROWS / TM)              // 64
#define NTRI  (NTILE * (NTILE + 1) / 2) // 2080

__global__ __launch_bounds__(256) void simexp_kernel(
    const bf16* __restrict__ zn, float* __restrict__ rowsum) {
  __shared__ __align__(16) bf16 ldsA[TM * BK];   // 16 KB
  __shared__ __align__(16) bf16 ldsB[TM * BK];   // 16 KB

  // decode linear tile id -> (bi, bj), bj <= bi
  int tid = blockIdx.x;
  int bi = (int)((sqrtf(8.0f * tid + 1.0f) - 1.0f) * 0.5f);
  while ((bi + 1) * (bi + 2) / 2 <= tid) ++bi;
  while (bi * (bi + 1) / 2 > tid) --bi;
  int bj = tid - bi * (bi + 1) / 2;

  const int t = threadIdx.x;
  const int wave = t >> 6, lane = t & 63;
  const int wr = wave >> 1, wc = wave & 1;
  const int quad = lane >> 4, l15 = lane & 15;
  const int rowA0 = bi * TM, rowB0 = bj * TM;

  f32x4 acc[4][4] = {};

  for (int k0 = 0; k0 < DDIM; k0 += BK) {
    __syncthreads();
    #pragma unroll
    for (int p = 0; p < 4; ++p) {
      int c = p * 256 + t;
      int row = c >> 3, c8 = c & 7;
      int gc8 = c8 ^ (row & 7);
      const bf16* gA = zn + (size_t)(rowA0 + row) * DDIM + k0 + gc8 * 8;
      const bf16* gB = zn + (size_t)(rowB0 + row) * DDIM + k0 + gc8 * 8;
      async16(gA, &ldsA[c * 8]);
      async16(gB, &ldsB[c * 8]);
    }
    __syncthreads();

    #pragma unroll
    for (int kk = 0; kk < BK; kk += 32) {
      const int kc8 = (kk >> 3) + quad;
      bf16x8 af[4], bg[4];
      #pragma unroll
      for (int mi = 0; mi < 4; ++mi) {
        int row = wr * 64 + mi * 16 + l15;
        int sc8 = kc8 ^ (row & 7);
        af[mi] = *(const bf16x8*)&ldsA[(row * 8 + sc8) * 8];
      }
      #pragma unroll
      for (int nj = 0; nj < 4; ++nj) {
        int row = wc * 64 + nj * 16 + l15;
        int sc8 = kc8 ^ (row & 7);
        bg[nj] = *(const bf16x8*)&ldsB[(row * 8 + sc8) * 8];
      }
      #pragma unroll
      for (int mi = 0; mi < 4; ++mi)
        #pragma unroll
        for (int nj = 0; nj < 4; ++nj)
          acc[mi][nj] = __builtin_amdgcn_mfma_f32_16x16x32_bf16(
              af[mi], bg[nj], acc[mi][nj], 0, 0, 0);
    }
  }

  // Epilogue: exp (diag masked), row sums -> rowsum[gi];
  // for off-diag tiles also col sums -> rowsum[gj] (symmetry).
  float cs[4] = {0.f, 0.f, 0.f, 0.f};
  #pragma unroll
  for (int mi = 0; mi < 4; ++mi) {
    float rs[4] = {0.f, 0.f, 0.f, 0.f};
    #pragma unroll
    for (int nj = 0; nj < 4; ++nj) {
      int gj = rowB0 + wc * 64 + nj * 16 + l15;
      #pragma unroll
      for (int r = 0; r < 4; ++r) {
        int gi = rowA0 + wr * 64 + mi * 16 + quad * 4 + r;
        float e = (gi == gj) ? 0.f : __expf(acc[mi][nj][r] * TINV);
        rs[r] += e;
        cs[nj] += e;
      }
    }
    #pragma unroll
    for (int r = 0; r < 4; ++r) {
      float s = rs[r];
      s += __shfl_xor(s, 1, 64);
      s += __shfl_xor(s, 2, 64);
      s += __shfl_xor(s, 4, 64);
      s += __shfl_xor(s, 8, 64);
      if (l15 == 0) {
        int gi = rowA0 + wr * 64 + mi * 16 + quad * 4 + r;
        atomicAdd(&rowsum[gi], s);
      }
    }
  }
  if (bi != bj) {
    #pragma unroll
    for (int nj = 0; nj < 4; ++nj) {
      float s = cs[nj];
      s += __shfl_xor(s, 16, 64);
      s += __shfl_xor(s, 32, 64);
      if (quad == 0) {
        int gj = rowB0 + wc * 64 + nj * 16 + l15;
        atomicAdd(&rowsum[gj], s);
      }
    }
  }
}

// ---------------- final scalar reduction -----------------------------------
__global__ __launch_bounds__(256) void finalize_kernel(
    const float* __restrict__ rowsum, const float* __restrict__ pos,
    float* __restrict__ out) {
  __shared__ float red[4];
  int t = threadIdx.x;
  float s = 0.f;
  for (int i = t; i < NROWS; i += 256) s += __logf(rowsum[i]);
  for (int i = t; i < BROWS; i += 256) s -= 2.f * pos[i];
  #pragma unroll
  for (int off = 32; off; off >>= 1) s += __shfl_xor(s, off, 64);
  if ((t & 63) == 0) red[t >> 6] = s;
  __syncthreads();
  if (t == 0) out[0] = (red[0] + red[1] + red[2] + red[3]) / (float)NROWS;
}

// ---------------- launch ----------------------------------------------------
extern "C" void kernel_launch(void* const* d_in, const int* in_sizes, int n_in,
                              void* d_out, int out_size, void* d_ws, size_t ws_size,
                              hipStream_t stream) {
  const float* z1 = (const float*)d_in[0];
  const float* z2 = (const float*)d_in[1];
  char* ws = (char*)d_ws;
  bf16*  zn     = (bf16*)ws;                               // 4 MB
  float* rowsum = (float*)(ws + 4194304);                  // 32 KB
  float* pos    = (float*)(ws + 4194304 + 32768);          // 16 KB
  float* out    = (float*)d_out;

  prep_kernel<<<BROWS / 4, 256, 0, stream>>>(z1, z2, zn, pos, rowsum);
  simexp_kernel<<<NTRI, 256, 0, stream>>>(zn, rowsum);
  finalize_kernel<<<1, 256, 0, stream>>>(rowsum, pos, out);
}